// Round 1
// baseline (1246.740 us; speedup 1.0000x reference)
//
#include <hip/hip_runtime.h>

#define D 128

// ---------------------------------------------------------------------------
// prep: Wt[k][j] = (k<128 ? W1[j][k] : W2[j][k-128]);  bsum[j] = b1[j]+b2[j]
// ---------------------------------------------------------------------------
__global__ __launch_bounds__(256) void prep_k(
    const float* __restrict__ W1, const float* __restrict__ b1,
    const float* __restrict__ W2, const float* __restrict__ b2,
    float* __restrict__ Wt, float* __restrict__ bsum) {
  int tid = blockIdx.x * 256 + threadIdx.x;
  if (tid < 256 * 128) {
    int k = tid >> 7, j = tid & 127;
    float v = (k < 128) ? W1[j * 128 + k] : W2[j * 128 + (k - 128)];
    Wt[tid] = v;
  }
  if (tid < 128) bsum[tid] = b1[tid] + b2[tid];
}

// ---------------------------------------------------------------------------
// scatter: agg[col] += w * x[row]   (32 threads per edge, float4 per thread)
// ---------------------------------------------------------------------------
__global__ __launch_bounds__(256) void scatter_k(
    const float* __restrict__ x, const int* __restrict__ ei,
    const float* __restrict__ ew, float* __restrict__ agg, int E) {
  int tid = blockIdx.x * 256 + threadIdx.x;
  int e = tid >> 5;
  if (e >= E) return;
  int q = tid & 31;
  int r = ei[e];
  int c = ei[E + e];
  float wt = ew[e];
  float4 v = ((const float4*)(x + (size_t)r * D))[q];
  float* dst = agg + (size_t)c * D + q * 4;
  unsafeAtomicAdd(dst + 0, wt * v.x);
  unsafeAtomicAdd(dst + 1, wt * v.y);
  unsafeAtomicAdd(dst + 2, wt * v.z);
  unsafeAtomicAdd(dst + 3, wt * v.w);
}

// ---------------------------------------------------------------------------
// fused: u = agg+x, v = agg*x staged in LDS; h = [u,v] @ Wt + bsum; leakyrelu
// Block: 256 threads, 64-node tile. Thread: 4 nodes x 8 outputs.
// LDS row stride 264 floats -> ty-groups hit distinct banks on a-reads.
// ---------------------------------------------------------------------------
__global__ __launch_bounds__(256) void fused_k(
    const float* __restrict__ x, const float* __restrict__ agg,
    const float* __restrict__ Wt, const float* __restrict__ bsum,
    float* __restrict__ out, int Nn) {
  constexpr int STR = 264;
  __shared__ float U[64 * STR];
  const int t = threadIdx.x;
  const int node0 = blockIdx.x * 64;

  // stage u,v (64 nodes x 256 k) into LDS, coalesced float4 reads
  #pragma unroll
  for (int i = 0; i < 8; ++i) {
    int f4 = t + i * 256;          // 0..2047
    int node = f4 >> 5;            // 32 float4 per node row
    int d4 = f4 & 31;
    int g = node0 + node;
    float4 a4 = make_float4(0.f, 0.f, 0.f, 0.f), x4 = a4;
    if (g < Nn) {
      a4 = ((const float4*)agg)[(size_t)g * 32 + d4];
      x4 = ((const float4*)x)[(size_t)g * 32 + d4];
    }
    float4 u4 = make_float4(a4.x + x4.x, a4.y + x4.y, a4.z + x4.z, a4.w + x4.w);
    float4 v4 = make_float4(a4.x * x4.x, a4.y * x4.y, a4.z * x4.z, a4.w * x4.w);
    *(float4*)&U[node * STR + d4 * 4]       = u4;
    *(float4*)&U[node * STR + 128 + d4 * 4] = v4;
  }
  __syncthreads();

  const int tx = t & 15, ty = t >> 4;
  const int j0 = tx * 8;
  float acc[4][8];
  #pragma unroll
  for (int m = 0; m < 4; ++m)
    #pragma unroll
    for (int j = 0; j < 8; ++j) acc[m][j] = 0.f;

  const float* ub = &U[(ty * 4) * STR];
  for (int k = 0; k < 256; k += 4) {
    float a[4][4];
    #pragma unroll
    for (int m = 0; m < 4; ++m)
      *(float4*)a[m] = *(const float4*)(ub + m * STR + k);
    #pragma unroll
    for (int kk = 0; kk < 4; ++kk) {
      const float* wrow = Wt + (k + kk) * 128 + j0;
      float4 bA = *(const float4*)(wrow);
      float4 bB = *(const float4*)(wrow + 4);
      float bb[8] = {bA.x, bA.y, bA.z, bA.w, bB.x, bB.y, bB.z, bB.w};
      #pragma unroll
      for (int m = 0; m < 4; ++m) {
        float av = a[m][kk];
        #pragma unroll
        for (int j = 0; j < 8; ++j) acc[m][j] += av * bb[j];
      }
    }
  }

  float bs[8];
  *(float4*)&bs[0] = *(const float4*)(bsum + j0);
  *(float4*)&bs[4] = *(const float4*)(bsum + j0 + 4);
  #pragma unroll
  for (int m = 0; m < 4; ++m) {
    int g = node0 + ty * 4 + m;
    if (g >= Nn) continue;
    float r[8];
    #pragma unroll
    for (int j = 0; j < 8; ++j) {
      float h = acc[m][j] + bs[j];
      r[j] = h > 0.f ? h : 0.2f * h;
    }
    ((float4*)out)[(size_t)g * 32 + (j0 >> 2)]     = *(float4*)&r[0];
    ((float4*)out)[(size_t)g * 32 + (j0 >> 2) + 1] = *(float4*)&r[4];
  }
}

// ---------------------------------------------------------------------------
extern "C" void kernel_launch(void* const* d_in, const int* in_sizes, int n_in,
                              void* d_out, int out_size, void* d_ws, size_t ws_size,
                              hipStream_t stream) {
  const float* x  = (const float*)d_in[0];
  const int*   ei = (const int*)d_in[1];
  const float* ew = (const float*)d_in[2];
  const float* W1 = (const float*)d_in[3];
  const float* b1 = (const float*)d_in[4];
  const float* W2 = (const float*)d_in[5];
  const float* b2 = (const float*)d_in[6];
  float* out = (float*)d_out;

  const int Nn = in_sizes[0] / D;   // 100000
  const int E  = in_sizes[2];       // 600000

  size_t aggBytes = (size_t)Nn * D * sizeof(float);
  size_t smallBytes = (size_t)(256 * 128 + 128) * sizeof(float);

  float *agg, *Wt;
  if (ws_size >= aggBytes + smallBytes) {
    agg = (float*)d_ws;
    Wt  = (float*)((char*)d_ws + aggBytes);
  } else {
    // fallback: use d_out as agg scratch (safe: each fused_k block reads agg
    // only for its own node tile before overwriting those same rows)
    agg = out;
    Wt  = (float*)d_ws;
  }
  float* bs = Wt + 256 * 128;

  hipMemsetAsync(agg, 0, aggBytes, stream);
  prep_k<<<128, 256, 0, stream>>>(W1, b1, W2, b2, Wt, bs);

  long long sthreads = (long long)E * 32;
  int sblocks = (int)((sthreads + 255) / 256);
  scatter_k<<<sblocks, 256, 0, stream>>>(x, ei, ew, agg, E);

  fused_k<<<(Nn + 63) / 64, 256, 0, stream>>>(x, agg, Wt, bs, out, Nn);
}

// Round 2
// 352.609 us; speedup vs baseline: 3.5358x; 3.5358x over previous
//
#include <hip/hip_runtime.h>

#define D 128

// ---------------------------------------------------------------------------
// prep: Wt[k][j] = (k<128 ? W1[j][k] : W2[j][k-128]);  bsum[j] = b1[j]+b2[j]
// ---------------------------------------------------------------------------
__global__ __launch_bounds__(256) void prep_k(
    const float* __restrict__ W1, const float* __restrict__ b1,
    const float* __restrict__ W2, const float* __restrict__ b2,
    float* __restrict__ Wt, float* __restrict__ bsum) {
  int tid = blockIdx.x * 256 + threadIdx.x;
  if (tid < 256 * 128) {
    int k = tid >> 7, j = tid & 127;
    float v = (k < 128) ? W1[j * 128 + k] : W2[j * 128 + (k - 128)];
    Wt[tid] = v;
  }
  if (tid < 128) bsum[tid] = b1[tid] + b2[tid];
}

// ---------------------------------------------------------------------------
// CSR build: histogram -> 3-kernel exclusive scan -> fill (bucket edges by col)
// cursor[] doubles as deg[] for the histogram, then as running fill cursor.
// ---------------------------------------------------------------------------
__global__ __launch_bounds__(256) void hist_k(
    const int* __restrict__ ei, int* __restrict__ cursor, int E) {
  int e = blockIdx.x * 256 + threadIdx.x;
  if (e < E) atomicAdd(&cursor[ei[E + e]], 1);
}

// block-level exclusive scan: 256 threads x 4 items = 1024/block
__global__ __launch_bounds__(256) void scan_block_k(
    const int* __restrict__ deg, int* __restrict__ rowptr,
    int* __restrict__ partials, int Nn) {
  __shared__ int sdata[256];
  int t = threadIdx.x;
  int base = blockIdx.x * 1024 + t * 4;
  int v[4];
  #pragma unroll
  for (int j = 0; j < 4; ++j) v[j] = (base + j < Nn) ? deg[base + j] : 0;
  int tsum = v[0] + v[1] + v[2] + v[3];
  sdata[t] = tsum;
  __syncthreads();
  for (int off = 1; off < 256; off <<= 1) {
    int add = (t >= off) ? sdata[t - off] : 0;
    __syncthreads();
    sdata[t] += add;
    __syncthreads();
  }
  int run = sdata[t] - tsum;  // exclusive prefix of this thread
  if (t == 255) partials[blockIdx.x] = sdata[255];
  #pragma unroll
  for (int j = 0; j < 4; ++j) {
    if (base + j < Nn) rowptr[base + j] = run;
    run += v[j];
  }
}

__global__ __launch_bounds__(128) void scan_partials_k(int* partials, int NB) {
  __shared__ int s[128];
  int t = threadIdx.x;
  int orig = (t < NB) ? partials[t] : 0;
  s[t] = orig;
  __syncthreads();
  for (int off = 1; off < 128; off <<= 1) {
    int add = (t >= off) ? s[t - off] : 0;
    __syncthreads();
    s[t] += add;
    __syncthreads();
  }
  if (t < NB) partials[t] = s[t] - orig;  // exclusive
}

__global__ __launch_bounds__(256) void add_offsets_k(
    int* __restrict__ rowptr, int* __restrict__ cursor,
    const int* __restrict__ partials, int Nn, int E) {
  int i = blockIdx.x * 256 + threadIdx.x;
  if (i < Nn) {
    int v = rowptr[i] + partials[i >> 10];
    rowptr[i] = v;
    cursor[i] = v;
  }
  if (i == 0) rowptr[Nn] = E;
}

__global__ __launch_bounds__(256) void fill_k(
    const int* __restrict__ ei, const float* __restrict__ ew,
    int* __restrict__ cursor, int* __restrict__ srcRow,
    float* __restrict__ srcW, int E) {
  int e = blockIdx.x * 256 + threadIdx.x;
  if (e >= E) return;
  int c = ei[E + e];
  int p = atomicAdd(&cursor[c], 1);
  srcRow[p] = ei[e];
  srcW[p] = ew[e];
}

// ---------------------------------------------------------------------------
// aggregate: one wave (64 lanes) per node, lane owns float2 of the row.
// 4-edge batching: 4 independent row-gathers in flight per iteration.
// ---------------------------------------------------------------------------
__global__ __launch_bounds__(256) void agg_k(
    const float* __restrict__ x, const int* __restrict__ rowptr,
    const int* __restrict__ srcRow, const float* __restrict__ srcW,
    float* __restrict__ agg, int Nn) {
  int node = blockIdx.x * 4 + (threadIdx.x >> 6);
  if (node >= Nn) return;
  int lane = threadIdx.x & 63;
  int beg = rowptr[node], end = rowptr[node + 1];
  float2 acc = make_float2(0.f, 0.f);
  int p = beg;
  for (; p + 4 <= end; p += 4) {
    int r0 = srcRow[p], r1 = srcRow[p + 1], r2 = srcRow[p + 2], r3 = srcRow[p + 3];
    float w0 = srcW[p], w1 = srcW[p + 1], w2 = srcW[p + 2], w3 = srcW[p + 3];
    float2 v0 = ((const float2*)(x + (size_t)r0 * D))[lane];
    float2 v1 = ((const float2*)(x + (size_t)r1 * D))[lane];
    float2 v2 = ((const float2*)(x + (size_t)r2 * D))[lane];
    float2 v3 = ((const float2*)(x + (size_t)r3 * D))[lane];
    acc.x += w0 * v0.x; acc.y += w0 * v0.y;
    acc.x += w1 * v1.x; acc.y += w1 * v1.y;
    acc.x += w2 * v2.x; acc.y += w2 * v2.y;
    acc.x += w3 * v3.x; acc.y += w3 * v3.y;
  }
  for (; p < end; ++p) {
    int r = srcRow[p];
    float w = srcW[p];
    float2 v = ((const float2*)(x + (size_t)r * D))[lane];
    acc.x += w * v.x; acc.y += w * v.y;
  }
  ((float2*)(agg + (size_t)node * D))[lane] = acc;
}

// ---------------------------------------------------------------------------
// fused: u = agg+x, v = agg*x staged in LDS; h = [u,v] @ Wt + bsum; leakyrelu
// ---------------------------------------------------------------------------
__global__ __launch_bounds__(256) void fused_k(
    const float* __restrict__ x, const float* __restrict__ agg,
    const float* __restrict__ Wt, const float* __restrict__ bsum,
    float* __restrict__ out, int Nn) {
  constexpr int STR = 264;
  __shared__ float U[64 * STR];
  const int t = threadIdx.x;
  const int node0 = blockIdx.x * 64;

  #pragma unroll
  for (int i = 0; i < 8; ++i) {
    int f4 = t + i * 256;
    int node = f4 >> 5;
    int d4 = f4 & 31;
    int g = node0 + node;
    float4 a4 = make_float4(0.f, 0.f, 0.f, 0.f), x4 = a4;
    if (g < Nn) {
      a4 = ((const float4*)agg)[(size_t)g * 32 + d4];
      x4 = ((const float4*)x)[(size_t)g * 32 + d4];
    }
    float4 u4 = make_float4(a4.x + x4.x, a4.y + x4.y, a4.z + x4.z, a4.w + x4.w);
    float4 v4 = make_float4(a4.x * x4.x, a4.y * x4.y, a4.z * x4.z, a4.w * x4.w);
    *(float4*)&U[node * STR + d4 * 4]       = u4;
    *(float4*)&U[node * STR + 128 + d4 * 4] = v4;
  }
  __syncthreads();

  const int tx = t & 15, ty = t >> 4;
  const int j0 = tx * 8;
  float acc[4][8];
  #pragma unroll
  for (int m = 0; m < 4; ++m)
    #pragma unroll
    for (int j = 0; j < 8; ++j) acc[m][j] = 0.f;

  const float* ub = &U[(ty * 4) * STR];
  for (int k = 0; k < 256; k += 4) {
    float a[4][4];
    #pragma unroll
    for (int m = 0; m < 4; ++m)
      *(float4*)a[m] = *(const float4*)(ub + m * STR + k);
    #pragma unroll
    for (int kk = 0; kk < 4; ++kk) {
      const float* wrow = Wt + (k + kk) * 128 + j0;
      float4 bA = *(const float4*)(wrow);
      float4 bB = *(const float4*)(wrow + 4);
      float bb[8] = {bA.x, bA.y, bA.z, bA.w, bB.x, bB.y, bB.z, bB.w};
      #pragma unroll
      for (int m = 0; m < 4; ++m) {
        float av = a[m][kk];
        #pragma unroll
        for (int j = 0; j < 8; ++j) acc[m][j] += av * bb[j];
      }
    }
  }

  float bs[8];
  *(float4*)&bs[0] = *(const float4*)(bsum + j0);
  *(float4*)&bs[4] = *(const float4*)(bsum + j0 + 4);
  #pragma unroll
  for (int m = 0; m < 4; ++m) {
    int g = node0 + ty * 4 + m;
    if (g >= Nn) continue;
    float r[8];
    #pragma unroll
    for (int j = 0; j < 8; ++j) {
      float h = acc[m][j] + bs[j];
      r[j] = h > 0.f ? h : 0.2f * h;
    }
    ((float4*)out)[(size_t)g * 32 + (j0 >> 2)]     = *(float4*)&r[0];
    ((float4*)out)[(size_t)g * 32 + (j0 >> 2) + 1] = *(float4*)&r[4];
  }
}

// ---------------------------------------------------------------------------
extern "C" void kernel_launch(void* const* d_in, const int* in_sizes, int n_in,
                              void* d_out, int out_size, void* d_ws, size_t ws_size,
                              hipStream_t stream) {
  const float* x  = (const float*)d_in[0];
  const int*   ei = (const int*)d_in[1];
  const float* ew = (const float*)d_in[2];
  const float* W1 = (const float*)d_in[3];
  const float* b1 = (const float*)d_in[4];
  const float* W2 = (const float*)d_in[5];
  const float* b2 = (const float*)d_in[6];
  float* out = (float*)d_out;

  const int Nn = in_sizes[0] / D;   // 100000
  const int E  = in_sizes[2];       // 600000
  const int NB = (Nn + 1023) / 1024;

  const size_t aggB    = (size_t)Nn * D * sizeof(float);          // mult of 16
  const size_t srcRowB = (size_t)E * sizeof(int);
  const size_t srcWB   = (size_t)E * sizeof(float);
  const size_t cursorB = (size_t)Nn * sizeof(int);
  const size_t rowptrB = (((size_t)(Nn + 1) * sizeof(int)) + 15) & ~(size_t)15;
  const size_t partB   = 1024;
  const size_t WtB     = 256 * 128 * sizeof(float);
  const size_t bsB     = 512;
  const size_t smallB  = srcRowB + srcWB + cursorB + rowptrB + partB + WtB + bsB;

  char* base = (char*)d_ws;
  float* agg;
  if (ws_size >= aggB + smallB) {
    agg = (float*)base;
    base += aggB;
  } else {
    // fallback: d_out as agg scratch (each fused_k block reads only its own
    // tile's agg rows before overwriting those same rows)
    agg = out;
  }
  int*   srcRow  = (int*)base;                base += srcRowB;
  float* srcW    = (float*)base;              base += srcWB;
  int*   cursor  = (int*)base;                base += cursorB;
  int*   rowptr  = (int*)base;                base += rowptrB;
  int*   partials= (int*)base;                base += partB;
  float* Wt      = (float*)base;              base += WtB;
  float* bs      = (float*)base;

  // CSR build
  hipMemsetAsync(cursor, 0, cursorB, stream);
  int eBlocks = (E + 255) / 256;
  hist_k<<<eBlocks, 256, 0, stream>>>(ei, cursor, E);
  scan_block_k<<<NB, 256, 0, stream>>>(cursor, rowptr, partials, Nn);
  scan_partials_k<<<1, 128, 0, stream>>>(partials, NB);
  add_offsets_k<<<(Nn + 255) / 256, 256, 0, stream>>>(rowptr, cursor, partials, Nn, E);
  fill_k<<<eBlocks, 256, 0, stream>>>(ei, ew, cursor, srcRow, srcW, E);

  prep_k<<<128, 256, 0, stream>>>(W1, b1, W2, b2, Wt, bs);

  // gather-aggregate (no atomics)
  agg_k<<<(Nn + 3) / 4, 256, 0, stream>>>(x, rowptr, srcRow, srcW, agg, Nn);

  // transform
  fused_k<<<(Nn + 63) / 64, 256, 0, stream>>>(x, agg, Wt, bs, out, Nn);
}